// Round 6
// baseline (257.718 us; speedup 1.0000x reference)
//
#include <hip/hip_runtime.h>
#include <hip/hip_bf16.h>
#include <cstdint>

// Problem constants
#define BB   16
#define PP   1024
#define EE   768
#define HID  768
#define NH   12
#define DH   64
#define NPB  (PP * EE)          // 786432 elements per batch
#define MROWS (BB * PP)         // 16384

typedef __bf16 bf16_t;
typedef __bf16 bf16x8 __attribute__((ext_vector_type(8)));
typedef float  f32x4  __attribute__((ext_vector_type(4)));

// Async global->LDS 16B DMA. LDS dest must be wave-uniform base + lane*16.
__device__ __forceinline__ void gld16(const void* g, void* l) {
    __builtin_amdgcn_global_load_lds(
        (const __attribute__((address_space(1))) void*)(uintptr_t)g,
        (__attribute__((address_space(3))) void*)(uint32_t)(uintptr_t)l,
        16, 0, 0);
}

// ---------------------------------------------------------------------------
// Stage 1: per-slice partial sums for batch-global LayerNorm stats
// ---------------------------------------------------------------------------
__global__ __launch_bounds__(256) void stats1_kernel(const float* __restrict__ x,
                                                     float* __restrict__ part) {
    int bid = blockIdx.x;
    int b = bid >> 6, s = bid & 63;
    const float4* xp = (const float4*)(x + (size_t)b * NPB + (size_t)s * 12288);
    float sum = 0.f, ss = 0.f;
#pragma unroll
    for (int i = 0; i < 12; ++i) {
        float4 v = xp[i * 256 + threadIdx.x];
        sum += v.x + v.y + v.z + v.w;
        ss  += v.x * v.x + v.y * v.y + v.z * v.z + v.w * v.w;
    }
#pragma unroll
    for (int off = 32; off > 0; off >>= 1) {
        sum += __shfl_down(sum, off, 64);
        ss  += __shfl_down(ss,  off, 64);
    }
    __shared__ float tmp[8];
    int wave = threadIdx.x >> 6, lane = threadIdx.x & 63;
    if (lane == 0) { tmp[wave * 2] = sum; tmp[wave * 2 + 1] = ss; }
    __syncthreads();
    if (threadIdx.x == 0) {
        part[bid * 2]     = tmp[0] + tmp[2] + tmp[4] + tmp[6];
        part[bid * 2 + 1] = tmp[1] + tmp[3] + tmp[5] + tmp[7];
    }
}

// ---------------------------------------------------------------------------
// prep: LDS-tiled weight transposes (coalesced both sides) + stats finalize.
// blocks [0,432): qkvT tiles ; [432,576): lwT tiles ; 576: stats2.
// ---------------------------------------------------------------------------
__global__ __launch_bounds__(256) void prep_kernel(const float* __restrict__ qkvw,
                                                   const float* __restrict__ linw,
                                                   const float* __restrict__ part,
                                                   bf16_t* __restrict__ qkvT,
                                                   bf16_t* __restrict__ lwT,
                                                   float* __restrict__ stats) {
    int bid = blockIdx.x;
    if (bid < 576) {
        __shared__ float lds[64][65];
        const float* src; bf16_t* dst; int r0, c0, W;
        if (bid < 432) {
            int tr = bid / 36, tc = bid - tr * 36;
            r0 = tr * 64; c0 = tc * 64; src = qkvw; W = 2304; dst = qkvT;
        } else {
            int bb = bid - 432;
            int tr = bb / 12, tc = bb - tr * 12;
            r0 = tr * 64; c0 = tc * 64; src = linw; W = 768; dst = lwT;
        }
        int t = threadIdx.x;
        int rr = t >> 4, cc4 = (t & 15) * 4;
#pragma unroll
        for (int j = 0; j < 4; ++j) {
            float4 v = *(const float4*)(src + (size_t)(r0 + rr + j * 16) * W + c0 + cc4);
            lds[rr + j * 16][cc4 + 0] = v.x;
            lds[rr + j * 16][cc4 + 1] = v.y;
            lds[rr + j * 16][cc4 + 2] = v.z;
            lds[rr + j * 16][cc4 + 3] = v.w;
        }
        __syncthreads();
        int cl = t >> 3, rgl = (t & 7) * 8;
#pragma unroll
        for (int jj = 0; jj < 2; ++jj) {
            int c = jj * 32 + cl;
            union { bf16_t h[8]; uint4 u; } o;
#pragma unroll
            for (int k = 0; k < 8; ++k) o.h[k] = (bf16_t)lds[rgl + k][c];
            *(uint4*)(dst + (size_t)(c0 + c) * 768 + r0 + rgl) = o.u;
        }
    } else {
        int wave = threadIdx.x >> 6, lane = threadIdx.x & 63;
#pragma unroll
        for (int j = 0; j < 4; ++j) {
            int b = wave * 4 + j;
            float sum = part[(b * 64 + lane) * 2];
            float ss  = part[(b * 64 + lane) * 2 + 1];
#pragma unroll
            for (int off = 32; off > 0; off >>= 1) {
                sum += __shfl_down(sum, off, 64);
                ss  += __shfl_down(ss,  off, 64);
            }
            if (lane == 0) {
                const float inv_n = 1.f / (float)NPB;
                float mean = sum * inv_n;
                float var  = ss * inv_n - mean * mean;
                stats[b * 2]     = mean;
                stats[b * 2 + 1] = rsqrtf(var + 1e-5f);
            }
        }
    }
}

__global__ __launch_bounds__(256) void ln_apply_kernel(const float* __restrict__ x,
                                                       const float* __restrict__ lnw,
                                                       const float* __restrict__ lnb,
                                                       const float* __restrict__ stats,
                                                       bf16_t* __restrict__ xn) {
    int i = (blockIdx.x * 256 + threadIdx.x) * 8;
    int b = i / NPB;
    int r = i - b * NPB;
    float mean = stats[b * 2], rstd = stats[b * 2 + 1];
    float4 x0 = *(const float4*)(x + i),     x1 = *(const float4*)(x + i + 4);
    float4 w0 = *(const float4*)(lnw + r),   w1 = *(const float4*)(lnw + r + 4);
    float4 c0 = *(const float4*)(lnb + r),   c1 = *(const float4*)(lnb + r + 4);
    union { bf16_t h[8]; uint4 u; } o;
    o.h[0] = (bf16_t)((x0.x - mean) * rstd * w0.x + c0.x);
    o.h[1] = (bf16_t)((x0.y - mean) * rstd * w0.y + c0.y);
    o.h[2] = (bf16_t)((x0.z - mean) * rstd * w0.z + c0.z);
    o.h[3] = (bf16_t)((x0.w - mean) * rstd * w0.w + c0.w);
    o.h[4] = (bf16_t)((x1.x - mean) * rstd * w1.x + c1.x);
    o.h[5] = (bf16_t)((x1.y - mean) * rstd * w1.y + c1.y);
    o.h[6] = (bf16_t)((x1.z - mean) * rstd * w1.z + c1.z);
    o.h[7] = (bf16_t)((x1.w - mean) * rstd * w1.w + c1.w);
    *(uint4*)(xn + i) = o.u;
}

// ---------------------------------------------------------------------------
// Core: 256x256 tile, 512 thr (8 waves 2Mx4N, wave tile 128x64), BK=32,
// TRIPLE-buffered (96KB, 1 blk/CU, 2 waves/SIMD), counted vmcnt(8): stage
// (t+2) issued at top of step t, never drains to 0 mid-loop. Per step the
// ds_reads for the 2nd MFMA phase (A4-7) are issued BEFORE the 1st MFMA
// cluster, so their latency retires under MFMA (m201 interleave). LDS lines
// 128B = paired rows (r | r+128), chunk slot rotated by line&7 (2-way free);
// staging source pre-swizzled to match.
// ---------------------------------------------------------------------------
__device__ __forceinline__ void core256_bk32(const bf16_t* __restrict__ A,
                                             const bf16_t* __restrict__ Bt,
                                             int mBase, int nBase,
                                             f32x4 acc[8][4], bf16_t* smem) {
    const int t = threadIdx.x, lane = t & 63, wave = t >> 6;
    const int wm = wave >> 2, wn = wave & 3;
    const int m16 = lane & 15, quad = lane >> 4;

    // staging: 4 gld16/thread/step (A 2, B 2). chunk c -> line l=c>>3,
    // slot s=c&7, logical lg=(s-(l&7))&7, row = l + (lg>>2)*128, kc = lg&3.
    const bf16_t* gsrc[4];
    int ldst[4];
#pragma unroll
    for (int j = 0; j < 2; ++j) {
        int c = t + 512 * j;
        int l = c >> 3, lg = ((c & 7) - (l & 7)) & 7;
        int row = l + (lg >> 2) * 128, kc = lg & 3;
        gsrc[j]     = A  + (size_t)(mBase + row) * 768 + kc * 8;
        ldst[j]     = c * 8;
        gsrc[2 + j] = Bt + (size_t)(nBase + row) * 768 + kc * 8;
        ldst[2 + j] = 8192 + c * 8;
    }

    // frag read offsets (elements, relative to step buffer)
    int aOff[8], bOff[4];
#pragma unroll
    for (int mf = 0; mf < 8; ++mf) {
        int l = mf * 16 + m16;                       // row % 128; half = wm
        aOff[mf] = l * 64 + (((wm * 4 + quad) + (l & 7)) & 7) * 8;
    }
#pragma unroll
    for (int nf = 0; nf < 4; ++nf) {
        int l = (wn & 1) * 64 + nf * 16 + m16;       // row % 128; half = wn>>1
        bOff[nf] = 8192 + l * 64 + ((((wn >> 1) * 4 + quad) + (l & 7)) & 7) * 8;
    }

    const f32x4 z = {0.f, 0.f, 0.f, 0.f};
#pragma unroll
    for (int mf = 0; mf < 8; ++mf)
#pragma unroll
        for (int nf = 0; nf < 4; ++nf) acc[mf][nf] = z;

    // prologue: stage steps 0,1 into bufs 0,1 (8 loads in flight)
#pragma unroll
    for (int j = 0; j < 4; ++j) gld16(gsrc[j], smem + ldst[j]);
#pragma unroll
    for (int j = 0; j < 4; ++j) gld16(gsrc[j] + 32, smem + 16384 + ldst[j]);

#pragma unroll
    for (int step = 0; step < 24; ++step) {
        const int cur = (step % 3) * 16384;
        // BARRIER_A: prior step's ds_reads retired in all waves before
        // stage(step+2) overwrites buf[(step+2)%3] == buf[(step-1)%3]
        asm volatile("s_waitcnt lgkmcnt(0)" ::: "memory");
        __builtin_amdgcn_sched_barrier(0);
        __builtin_amdgcn_s_barrier();
        if (step + 2 < 24) {
            const int nb = ((step + 2) % 3) * 16384;
            const int kq = (step + 2) * 32;
#pragma unroll
            for (int j = 0; j < 4; ++j)
                gld16(gsrc[j] + kq, smem + nb + ldst[j]);
        }
        // counted wait: stage(step) done; stages step+1/step+2 stay in flight
        if (step < 22)       asm volatile("s_waitcnt vmcnt(8)" ::: "memory");
        else if (step == 22) asm volatile("s_waitcnt vmcnt(4)" ::: "memory");
        else                 asm volatile("s_waitcnt vmcnt(0)" ::: "memory");
        __builtin_amdgcn_sched_barrier(0);
        __builtin_amdgcn_s_barrier();    // BARRIER_B: buf[step] globally ready

        // phase-0 frags first, then issue phase-1 A-reads BEFORE MFMA so
        // their latency hides under the first 16-MFMA cluster.
        bf16x8 af0[4], bfv[4], af1[4];
#pragma unroll
        for (int f = 0; f < 4; ++f) af0[f] = *(const bf16x8*)(smem + cur + aOff[f]);
#pragma unroll
        for (int f = 0; f < 4; ++f) bfv[f] = *(const bf16x8*)(smem + cur + bOff[f]);
#pragma unroll
        for (int f = 0; f < 4; ++f) af1[f] = *(const bf16x8*)(smem + cur + aOff[4 + f]);
        __builtin_amdgcn_s_setprio(1);
#pragma unroll
        for (int mf = 0; mf < 4; ++mf)
#pragma unroll
            for (int nf = 0; nf < 4; ++nf)
                acc[mf][nf] = __builtin_amdgcn_mfma_f32_16x16x32_bf16(
                    af0[mf], bfv[nf], acc[mf][nf], 0, 0, 0);
#pragma unroll
        for (int mf = 0; mf < 4; ++mf)
#pragma unroll
            for (int nf = 0; nf < 4; ++nf)
                acc[4 + mf][nf] = __builtin_amdgcn_mfma_f32_16x16x32_bf16(
                    af1[mf], bfv[nf], acc[4 + mf][nf], 0, 0, 0);
        __builtin_amdgcn_s_setprio(0);
    }
}

// ---------------------------------------------------------------------------
// GEMM1: proj = xn @ qkv. 256x256 tile, grid (9,64) = 576 blocks. Each wave
// owns one 64-col group (g64 = tx*4+wn) x 128 rows -> independent per-wave
// epilogues in private 9KB LDS slots (two 64-row passes).
// ---------------------------------------------------------------------------
__global__ __launch_bounds__(512, 2) void gemm_qkv_kernel(const bf16_t* __restrict__ xn,
                                                          const bf16_t* __restrict__ qkvT,
                                                          bf16_t* __restrict__ q,
                                                          bf16_t* __restrict__ kt,
                                                          bf16_t* __restrict__ vt) {
    __shared__ bf16_t smem[49152];   // 96KB: 3 x (A 16KB | B 16KB)
    const int t = threadIdx.x, lane = t & 63, wave = t >> 6;
    const int wm = wave >> 2, wn = wave & 3;
    const int m16 = lane & 15, quad = lane >> 4;

    // XCD swizzle: 576 = 8 * 72, bijective.
    const int lb = blockIdx.y * 9 + blockIdx.x;
    const int id = (lb & 7) * 72 + (lb >> 3);
    const int tx = id % 9, ty = id / 9;
    const int mBase = ty * 256, nBase = tx * 256;

    f32x4 acc[8][4];
    core256_bk32(xn, qkvT, mBase, nBase, acc, smem);

    __syncthreads();   // step-23 readers done before slots overwrite buffers
    bf16_t* slot = smem + wave * 4608;   // 64 x 72 elements
    const int b = mBase >> 10, p0 = mBase & 1023;
    const int g64 = tx * 4 + wn;
    const int cls = g64 % 3, h = g64 / 3;

#pragma unroll
    for (int pass = 0; pass < 2; ++pass) {
        if (cls == 0) {
            // q: row-major (B,P,768)
#pragma unroll
            for (int mf = 0; mf < 4; ++mf)
#pragma unroll
                for (int nf = 0; nf < 4; ++nf)
#pragma unroll
                    for (int i = 0; i < 4; ++i)
                        slot[(mf * 16 + quad * 4 + i) * 72 + nf * 16 + m16] =
                            (bf16_t)acc[pass * 4 + mf][nf][i];
            asm volatile("s_waitcnt lgkmcnt(0)" ::: "memory");
            __builtin_amdgcn_sched_barrier(0);
#pragma unroll
            for (int j = 0; j < 8; ++j) {
                int r = j * 8 + (lane >> 3), cc = lane & 7;
                bf16x8 val = *(const bf16x8*)(slot + r * 72 + cc * 8);
                *(bf16x8*)(q + ((size_t)(b * 1024 + p0 + wm * 128 + pass * 64 + r)) * 768 +
                           h * 64 + cc * 8) = val;
            }
        } else {
            // k/v: transposed (B,H,64,P) via per-wave [c][72] transpose
            bf16_t* dst = (cls == 1) ? kt : vt;
            const size_t bh = (size_t)(b * 12 + h);
#pragma unroll
            for (int mf = 0; mf < 4; ++mf)
#pragma unroll
                for (int nf = 0; nf < 4; ++nf) {
                    int c = nf * 16 + m16;
                    union { bf16_t hh[4]; uint2 u; } pk;
#pragma unroll
                    for (int i = 0; i < 4; ++i)
                        pk.hh[i] = (bf16_t)acc[pass * 4 + mf][nf][i];
                    *(uint2*)(slot + c * 72 + mf * 16 + quad * 4) = pk.u;
                }
            asm volatile("s_waitcnt lgkmcnt(0)" ::: "memory");
            __builtin_amdgcn_sched_barrier(0);
#pragma unroll
            for (int j = 0; j < 8; ++j) {
                int c = (lane >> 3) + j * 8, r8 = (lane & 7) * 8;
                bf16x8 val = *(const bf16x8*)(slot + c * 72 + r8);
                *(bf16x8*)(dst + (bh * 64 + c) * 1024 + p0 + wm * 128 +
                           pass * 64 + r8) = val;
            }
        }
        if (pass == 0) {
            asm volatile("s_waitcnt lgkmcnt(0)" ::: "memory");
            __builtin_amdgcn_sched_barrier(0);
        }
    }
}

// ---------------------------------------------------------------------------
// kvu: fused T = K^T V (per head) then U = T @ lin_w slice, T never leaves
// the block. grid (192).
// ---------------------------------------------------------------------------
__global__ __launch_bounds__(256) void kvu_kernel(const bf16_t* __restrict__ kt,
                                                  const bf16_t* __restrict__ vt,
                                                  const bf16_t* __restrict__ lwT,
                                                  bf16_t* __restrict__ ut) {
    __shared__ float red[4 * 64 * 65];   // 66.6 KB
    const int bh = blockIdx.x;
    const int b = bh / NH, h = bh - b * NH;
    const bf16_t* Kb = kt + (size_t)bh * DH * PP;
    const bf16_t* Vb = vt + (size_t)bh * DH * PP;
    const int t = threadIdx.x;
    const int lane = t & 63, wave = t >> 6;
    const int m16 = lane & 15, quad = lane >> 4;
    const f32x4 z = {0.f, 0.f, 0.f, 0.f};

    // ---- phase A: T partials ----
    {
        f32x4 acc[4][4];
#pragma unroll
        for (int mm = 0; mm < 4; ++mm)
#pragma unroll
            for (int nn = 0; nn < 4; ++nn) acc[mm][nn] = z;
        for (int ks = 0; ks < 8; ++ks) {
            int kb = wave * 256 + ks * 32 + quad * 8;
            bf16x8 af[4], bfv[4];
#pragma unroll
            for (int mm = 0; mm < 4; ++mm)
                af[mm] = *(const bf16x8*)(Kb + (size_t)(mm * 16 + m16) * PP + kb);
#pragma unroll
            for (int nn = 0; nn < 4; ++nn)
                bfv[nn] = *(const bf16x8*)(Vb + (size_t)(nn * 16 + m16) * PP + kb);
#pragma unroll
            for (int mm = 0; mm < 4; ++mm)
#pragma unroll
                for (int nn = 0; nn < 4; ++nn)
                    acc[mm][nn] = __builtin_amdgcn_mfma_f32_16x16x32_bf16(
                        af[mm], bfv[nn], acc[mm][nn], 0, 0, 0);
        }
#pragma unroll
        for (int mm = 0; mm < 4; ++mm)
#pragma unroll
            for (int nn = 0; nn < 4; ++nn)
#pragma unroll
                for (int i = 0; i < 4; ++i)
                    red[wave * 4160 + (mm * 16 + quad * 4 + i) * 65 + nn * 16 + m16] =
                        acc[mm][nn][i];
    }
    __syncthreads();

    // ---- build T hi/lo frags (u-GEMM A operand layout) ----
    const int wm = wave >> 1, wn = wave & 1;
    bf16x8 ah[2][2], al[2][2];
#pragma unroll
    for (int mm = 0; mm < 2; ++mm)
#pragma unroll
        for (int ks = 0; ks < 2; ++ks) {
            int d1 = wm * 32 + mm * 16 + m16;
            int base = d1 * 65 + ks * 32 + quad * 8;
#pragma unroll
            for (int e = 0; e < 8; ++e) {
                float s = red[base + e] + red[4160 + base + e] +
                          red[8320 + base + e] + red[12480 + base + e];
                bf16_t hi = (bf16_t)s;
                ah[mm][ks][e] = hi;
                al[mm][ks][e] = (bf16_t)(s - (float)hi);
            }
        }

    // ---- phase B: U = T @ lwT-slice, 3 x 256-col chunks ----
#pragma unroll
    for (int ny = 0; ny < 3; ++ny) {
        const int nBase = ny * 256;
        f32x4 acc2[2][8];
#pragma unroll
        for (int mm = 0; mm < 2; ++mm)
#pragma unroll
            for (int nn = 0; nn < 8; ++nn) acc2[mm][nn] = z;
#pragma unroll
        for (int ks = 0; ks < 2; ++ks) {
            bf16x8 bfr[8];
#pragma unroll
            for (int nn = 0; nn < 8; ++nn)
                bfr[nn] = *(const bf16x8*)(
                    lwT + (size_t)(nBase + wn * 128 + nn * 16 + m16) * 768 +
                    h * 64 + ks * 32 + quad * 8);
#pragma unroll
            for (int mm = 0; mm < 2; ++mm)
#pragma unroll
                for (int nn = 0; nn < 8; ++nn) {
                    acc2[mm][nn] = __builtin_amdgcn_mfma_f32_16x16x32_bf16(
                        ah[mm][ks], bfr[nn], acc2[mm][nn], 0, 0, 0);
                    acc2[mm][nn] = __builtin_amdgcn_mfma_f32_16x16x32_bf16(
                        al[mm][ks], bfr[nn], acc2[mm][nn], 0, 0, 0);
                }
        }
#pragma unroll
        for (int mm = 0; mm < 2; ++mm)
#pragma unroll
            for (int nn = 0; nn < 8; ++nn) {
                int e  = nBase + wn * 128 + nn * 16 + m16;
                int d1 = wm * 32 + mm * 16 + quad * 4;
                union { bf16_t hh[4]; uint2 u; } pk;
#pragma unroll
                for (int i = 0; i < 4; ++i) pk.hh[i] = (bf16_t)acc2[mm][nn][i];
                *(uint2*)(ut + ((size_t)b * 768 + e) * 768 + h * 64 + d1) = pk.u;
            }
    }
}

// ---------------------------------------------------------------------------
// Final GEMM: out = relu(q @ U^b + lin_b) + x (fp32 out). 256x256 tile,
// grid (3,64) = 192 blocks, same interleaved core.
// ---------------------------------------------------------------------------
__global__ __launch_bounds__(512, 2) void gemm_out_kernel(const bf16_t* __restrict__ q,
                                                          const bf16_t* __restrict__ ut,
                                                          const float* __restrict__ linb,
                                                          const float* __restrict__ x,
                                                          float* __restrict__ out) {
    __shared__ bf16_t smem[49152];
    const int lb = blockIdx.y * 3 + blockIdx.x;
    const int id = (lb & 7) * 24 + (lb >> 3);   // 192 = 8*24, bijective
    const int tx = id % 3, ty = id / 3;
    const int mBase = ty * 256, nBase = tx * 256;
    const int b = mBase >> 10;

    f32x4 acc[8][4];
    core256_bk32(q, ut + (size_t)b * 768 * 768, mBase, nBase, acc, smem);

    const int lane = threadIdx.x & 63, wave = threadIdx.x >> 6;
    const int wm = wave >> 2, wn = wave & 3;
    const int m16 = lane & 15, quad = lane >> 4;
#pragma unroll
    for (int mf = 0; mf < 8; ++mf) {
#pragma unroll
        for (int i = 0; i < 4; ++i) {
            size_t row = mBase + wm * 128 + mf * 16 + quad * 4 + i;
#pragma unroll
            for (int nf = 0; nf < 4; ++nf) {
                int col = nBase + wn * 64 + nf * 16 + m16;
                float v = acc[mf][nf][i] + linb[col];
                v = fmaxf(v, 0.f) + x[row * EE + col];
                out[row * EE + col] = v;
            }
        }
    }
}

// ---------------------------------------------------------------------------
// Launch
// ---------------------------------------------------------------------------
extern "C" void kernel_launch(void* const* d_in, const int* in_sizes, int n_in,
                              void* d_out, int out_size, void* d_ws, size_t ws_size,
                              hipStream_t stream) {
    const float* x    = (const float*)d_in[0];
    const float* lnw  = (const float*)d_in[1];
    const float* lnb  = (const float*)d_in[2];
    const float* qkvw = (const float*)d_in[3];
    const float* linw = (const float*)d_in[4];
    const float* linb = (const float*)d_in[5];
    float* out = (float*)d_out;
    char* ws = (char*)d_ws;

    // Workspace layout (bytes), total ~105.4 MB. Rotation:
    //   xn dead after gemm_qkv -> ut lives there (kvu reads kt/vt while
    //   writing ut, so ut must NOT alias kt/vt).
    float*  part  = (float*)(ws + 0);          //  8192 B
    float*  stats = (float*)(ws + 8192);       //   128 B
    bf16_t* xn    = (bf16_t*)(ws + 8448);      //  25165824 B
    bf16_t* qkvT  = (bf16_t*)(ws + 25174272);  //   3538944 B
    bf16_t* lwT   = (bf16_t*)(ws + 28713216);  //   1179648 B
    bf16_t* q     = (bf16_t*)(ws + 29892864);  //  25165824 B  (B,P,HID)
    bf16_t* kt    = (bf16_t*)(ws + 55058688);  //  25165824 B
    bf16_t* vt    = (bf16_t*)(ws + 80224512);  //  25165824 B -> end 105390336
    bf16_t* ut    = xn;                        //  18874368 B (xn dead after qkv)

    stats1_kernel<<<dim3(BB * 64), dim3(256), 0, stream>>>(x, part);
    prep_kernel<<<dim3(577), dim3(256), 0, stream>>>(qkvw, linw, part, qkvT, lwT, stats);
    ln_apply_kernel<<<dim3(6144), dim3(256), 0, stream>>>(x, lnw, lnb, stats, xn);
    gemm_qkv_kernel<<<dim3(9, 64), dim3(512), 0, stream>>>(xn, qkvT, q, kt, vt);
    kvu_kernel<<<dim3(192), dim3(256), 0, stream>>>(kt, vt, lwT, ut);
    gemm_out_kernel<<<dim3(3, 64), dim3(512), 0, stream>>>(q, ut, linb, x, out);
}

// Round 7
// 254.081 us; speedup vs baseline: 1.0143x; 1.0143x over previous
//
#include <hip/hip_runtime.h>
#include <hip/hip_bf16.h>
#include <cstdint>

// Problem constants
#define BB   16
#define PP   1024
#define EE   768
#define HID  768
#define NH   12
#define DH   64
#define NPB  (PP * EE)          // 786432 elements per batch
#define MROWS (BB * PP)         // 16384

typedef __bf16 bf16_t;
typedef __bf16 bf16x8 __attribute__((ext_vector_type(8)));
typedef float  f32x4  __attribute__((ext_vector_type(4)));

// Async global->LDS 16B DMA. LDS dest must be wave-uniform base + lane*16.
__device__ __forceinline__ void gld16(const void* g, void* l) {
    __builtin_amdgcn_global_load_lds(
        (const __attribute__((address_space(1))) void*)(uintptr_t)g,
        (__attribute__((address_space(3))) void*)(uint32_t)(uintptr_t)l,
        16, 0, 0);
}

// ---------------------------------------------------------------------------
// Stage 1: per-slice partial sums for batch-global LayerNorm stats
// ---------------------------------------------------------------------------
__global__ __launch_bounds__(256) void stats1_kernel(const float* __restrict__ x,
                                                     float* __restrict__ part) {
    int bid = blockIdx.x;
    int b = bid >> 6, s = bid & 63;
    const float4* xp = (const float4*)(x + (size_t)b * NPB + (size_t)s * 12288);
    float sum = 0.f, ss = 0.f;
#pragma unroll
    for (int i = 0; i < 12; ++i) {
        float4 v = xp[i * 256 + threadIdx.x];
        sum += v.x + v.y + v.z + v.w;
        ss  += v.x * v.x + v.y * v.y + v.z * v.z + v.w * v.w;
    }
#pragma unroll
    for (int off = 32; off > 0; off >>= 1) {
        sum += __shfl_down(sum, off, 64);
        ss  += __shfl_down(ss,  off, 64);
    }
    __shared__ float tmp[8];
    int wave = threadIdx.x >> 6, lane = threadIdx.x & 63;
    if (lane == 0) { tmp[wave * 2] = sum; tmp[wave * 2 + 1] = ss; }
    __syncthreads();
    if (threadIdx.x == 0) {
        part[bid * 2]     = tmp[0] + tmp[2] + tmp[4] + tmp[6];
        part[bid * 2 + 1] = tmp[1] + tmp[3] + tmp[5] + tmp[7];
    }
}

// ---------------------------------------------------------------------------
// prep: LDS-tiled weight transposes (coalesced both sides) + stats finalize.
// blocks [0,432): qkvT tiles ; [432,576): lwT tiles ; 576: stats2.
// ---------------------------------------------------------------------------
__global__ __launch_bounds__(256) void prep_kernel(const float* __restrict__ qkvw,
                                                   const float* __restrict__ linw,
                                                   const float* __restrict__ part,
                                                   bf16_t* __restrict__ qkvT,
                                                   bf16_t* __restrict__ lwT,
                                                   float* __restrict__ stats) {
    int bid = blockIdx.x;
    if (bid < 576) {
        __shared__ float lds[64][65];
        const float* src; bf16_t* dst; int r0, c0, W;
        if (bid < 432) {
            int tr = bid / 36, tc = bid - tr * 36;
            r0 = tr * 64; c0 = tc * 64; src = qkvw; W = 2304; dst = qkvT;
        } else {
            int bb = bid - 432;
            int tr = bb / 12, tc = bb - tr * 12;
            r0 = tr * 64; c0 = tc * 64; src = linw; W = 768; dst = lwT;
        }
        int t = threadIdx.x;
        int rr = t >> 4, cc4 = (t & 15) * 4;
#pragma unroll
        for (int j = 0; j < 4; ++j) {
            float4 v = *(const float4*)(src + (size_t)(r0 + rr + j * 16) * W + c0 + cc4);
            lds[rr + j * 16][cc4 + 0] = v.x;
            lds[rr + j * 16][cc4 + 1] = v.y;
            lds[rr + j * 16][cc4 + 2] = v.z;
            lds[rr + j * 16][cc4 + 3] = v.w;
        }
        __syncthreads();
        int cl = t >> 3, rgl = (t & 7) * 8;
#pragma unroll
        for (int jj = 0; jj < 2; ++jj) {
            int c = jj * 32 + cl;
            union { bf16_t h[8]; uint4 u; } o;
#pragma unroll
            for (int k = 0; k < 8; ++k) o.h[k] = (bf16_t)lds[rgl + k][c];
            *(uint4*)(dst + (size_t)(c0 + c) * 768 + r0 + rgl) = o.u;
        }
    } else {
        int wave = threadIdx.x >> 6, lane = threadIdx.x & 63;
#pragma unroll
        for (int j = 0; j < 4; ++j) {
            int b = wave * 4 + j;
            float sum = part[(b * 64 + lane) * 2];
            float ss  = part[(b * 64 + lane) * 2 + 1];
#pragma unroll
            for (int off = 32; off > 0; off >>= 1) {
                sum += __shfl_down(sum, off, 64);
                ss  += __shfl_down(ss,  off, 64);
            }
            if (lane == 0) {
                const float inv_n = 1.f / (float)NPB;
                float mean = sum * inv_n;
                float var  = ss * inv_n - mean * mean;
                stats[b * 2]     = mean;
                stats[b * 2 + 1] = rsqrtf(var + 1e-5f);
            }
        }
    }
}

__global__ __launch_bounds__(256) void ln_apply_kernel(const float* __restrict__ x,
                                                       const float* __restrict__ lnw,
                                                       const float* __restrict__ lnb,
                                                       const float* __restrict__ stats,
                                                       bf16_t* __restrict__ xn) {
    int i = (blockIdx.x * 256 + threadIdx.x) * 8;
    int b = i / NPB;
    int r = i - b * NPB;
    float mean = stats[b * 2], rstd = stats[b * 2 + 1];
    float4 x0 = *(const float4*)(x + i),     x1 = *(const float4*)(x + i + 4);
    float4 w0 = *(const float4*)(lnw + r),   w1 = *(const float4*)(lnw + r + 4);
    float4 c0 = *(const float4*)(lnb + r),   c1 = *(const float4*)(lnb + r + 4);
    union { bf16_t h[8]; uint4 u; } o;
    o.h[0] = (bf16_t)((x0.x - mean) * rstd * w0.x + c0.x);
    o.h[1] = (bf16_t)((x0.y - mean) * rstd * w0.y + c0.y);
    o.h[2] = (bf16_t)((x0.z - mean) * rstd * w0.z + c0.z);
    o.h[3] = (bf16_t)((x0.w - mean) * rstd * w0.w + c0.w);
    o.h[4] = (bf16_t)((x1.x - mean) * rstd * w1.x + c1.x);
    o.h[5] = (bf16_t)((x1.y - mean) * rstd * w1.y + c1.y);
    o.h[6] = (bf16_t)((x1.z - mean) * rstd * w1.z + c1.z);
    o.h[7] = (bf16_t)((x1.w - mean) * rstd * w1.w + c1.w);
    *(uint4*)(xn + i) = o.u;
}

// ---------------------------------------------------------------------------
// Core: 256x256 tile, 512 thr (8 waves 2Mx4N, wave tile 128x64), BK=32,
// 3 one-K-tile buffers (96KB), m201 phase cadence. 24 K-tiles, 2 phases each:
//   P1: read A0-3+B0-3 (8 b128); issue 2 gld16 (kt+2); s_barrier;
//       lgkmcnt(0)+sched_barrier; setprio(1) 16 MFMA setprio(0); s_barrier
//   P2: read A4-7 (4 b128, B kept live); issue 2 gld16; same cadence;
//       then once-per-K-tile gate: vmcnt(4) (kt+1 landed, kt+2 in flight,
//       >=4 phases of stage->use slack) + s_barrier. Drains to 0 only at
//       kt=22 (tail). LDS rows 64B, chunk slot = (logical + row)&3 rotation
//       (2-way free); staging source pre-swizzled to match.
// ---------------------------------------------------------------------------
__device__ __forceinline__ void core256_ph(const bf16_t* __restrict__ A,
                                           const bf16_t* __restrict__ Bt,
                                           int mBase, int nBase,
                                           f32x4 acc[8][4], bf16_t* smem) {
    const int t = threadIdx.x, lane = t & 63, wave = t >> 6;
    const int wm = wave >> 2, wn = wave & 3;
    const int m16 = lane & 15, quad = lane >> 4;

    // staging: per K-tile 4 gld16/thread (A chunks {t,t+512}, B same).
    // chunk c -> row l=c>>2, slot s=c&3, logical lg=(s-(l&3))&3, kchunk=lg.
    const bf16_t* ga[2]; const bf16_t* gb[2]; int la[2], lb[2];
#pragma unroll
    for (int j = 0; j < 2; ++j) {
        int c = t + 512 * j;
        int l = c >> 2, lg = ((c & 3) - (l & 3)) & 3;
        ga[j] = A  + (size_t)(mBase + l) * 768 + lg * 8;
        la[j] = c * 8;
        gb[j] = Bt + (size_t)(nBase + l) * 768 + lg * 8;
        lb[j] = 8192 + c * 8;
    }

    // frag read offsets (elements, relative to buffer base)
    int aOff[8], bOff[4];
#pragma unroll
    for (int mf = 0; mf < 8; ++mf) {
        int l = wm * 128 + mf * 16 + m16;
        aOff[mf] = l * 32 + ((quad + l) & 3) * 8;
    }
#pragma unroll
    for (int nf = 0; nf < 4; ++nf) {
        int l = wn * 64 + nf * 16 + m16;
        bOff[nf] = 8192 + l * 32 + ((quad + l) & 3) * 8;
    }

    const f32x4 z = {0.f, 0.f, 0.f, 0.f};
#pragma unroll
    for (int mf = 0; mf < 8; ++mf)
#pragma unroll
        for (int nf = 0; nf < 4; ++nf) acc[mf][nf] = z;

    // prologue: stage kt0 -> buf0, kt1 -> buf1
#pragma unroll
    for (int j = 0; j < 2; ++j) { gld16(ga[j], smem + la[j]); gld16(gb[j], smem + lb[j]); }
#pragma unroll
    for (int j = 0; j < 2; ++j) { gld16(ga[j] + 32, smem + 16384 + la[j]); gld16(gb[j] + 32, smem + 16384 + lb[j]); }
    asm volatile("s_waitcnt vmcnt(4)" ::: "memory");   // kt0 landed, kt1 in flight
    __builtin_amdgcn_sched_barrier(0);
    __builtin_amdgcn_s_barrier();

#pragma unroll
    for (int kt = 0; kt < 24; ++kt) {
        const int cur = (kt % 3) * 16384;
        const int nxt = ((kt + 2) % 3) * 16384;
        const int kq  = (kt + 2) * 32;
        bf16x8 af[4], bfv[4];

        // ---- phase 1: quadrant mf0-3 x nf0-3 ----
#pragma unroll
        for (int f = 0; f < 4; ++f) af[f]  = *(const bf16x8*)(smem + cur + aOff[f]);
#pragma unroll
        for (int f = 0; f < 4; ++f) bfv[f] = *(const bf16x8*)(smem + cur + bOff[f]);
        if (kt + 2 < 24) { gld16(ga[0] + kq, smem + nxt + la[0]); gld16(gb[0] + kq, smem + nxt + lb[0]); }
        __builtin_amdgcn_s_barrier();
        asm volatile("s_waitcnt lgkmcnt(0)" ::: "memory");
        __builtin_amdgcn_sched_barrier(0);
        __builtin_amdgcn_s_setprio(1);
#pragma unroll
        for (int mf = 0; mf < 4; ++mf)
#pragma unroll
            for (int nf = 0; nf < 4; ++nf)
                acc[mf][nf] = __builtin_amdgcn_mfma_f32_16x16x32_bf16(
                    af[mf], bfv[nf], acc[mf][nf], 0, 0, 0);
        __builtin_amdgcn_s_setprio(0);
        __builtin_amdgcn_s_barrier();

        // ---- phase 2: quadrant mf4-7 x nf0-3 (B frags kept live) ----
#pragma unroll
        for (int f = 0; f < 4; ++f) af[f] = *(const bf16x8*)(smem + cur + aOff[4 + f]);
        if (kt + 2 < 24) { gld16(ga[1] + kq, smem + nxt + la[1]); gld16(gb[1] + kq, smem + nxt + lb[1]); }
        __builtin_amdgcn_s_barrier();
        asm volatile("s_waitcnt lgkmcnt(0)" ::: "memory");
        __builtin_amdgcn_sched_barrier(0);
        __builtin_amdgcn_s_setprio(1);
#pragma unroll
        for (int mf = 0; mf < 4; ++mf)
#pragma unroll
            for (int nf = 0; nf < 4; ++nf)
                acc[4 + mf][nf] = __builtin_amdgcn_mfma_f32_16x16x32_bf16(
                    af[mf], bfv[nf], acc[4 + mf][nf], 0, 0, 0);
        __builtin_amdgcn_s_setprio(0);
        // once-per-K-tile gate for buf[kt+1]
        if (kt < 23) {
            if (kt < 22) asm volatile("s_waitcnt vmcnt(4)" ::: "memory");
            else         asm volatile("s_waitcnt vmcnt(0)" ::: "memory");
            __builtin_amdgcn_sched_barrier(0);
        }
        __builtin_amdgcn_s_barrier();
    }
}

// ---------------------------------------------------------------------------
// GEMM1: proj = xn @ qkv. 256x256 tile, grid (9,64) = 576 blocks. Each wave
// owns one 64-col group (g64 = tx*4+wn) x 128 rows -> independent per-wave
// epilogues in private 9KB LDS slots (two 64-row passes).
// ---------------------------------------------------------------------------
__global__ __launch_bounds__(512, 2) void gemm_qkv_kernel(const bf16_t* __restrict__ xn,
                                                          const bf16_t* __restrict__ qkvT,
                                                          bf16_t* __restrict__ q,
                                                          bf16_t* __restrict__ kt,
                                                          bf16_t* __restrict__ vt) {
    __shared__ bf16_t smem[49152];   // 96KB: 3 x (A 16KB | B 16KB)
    const int t = threadIdx.x, lane = t & 63, wave = t >> 6;
    const int wm = wave >> 2, wn = wave & 3;
    const int m16 = lane & 15, quad = lane >> 4;

    // XCD swizzle: 576 = 8 * 72, bijective.
    const int lb = blockIdx.y * 9 + blockIdx.x;
    const int id = (lb & 7) * 72 + (lb >> 3);
    const int tx = id % 9, ty = id / 9;
    const int mBase = ty * 256, nBase = tx * 256;

    f32x4 acc[8][4];
    core256_ph(xn, qkvT, mBase, nBase, acc, smem);

    __syncthreads();   // K-loop fully retired before slots overwrite buffers
    bf16_t* slot = smem + wave * 4608;   // 64 x 72 elements
    const int b = mBase >> 10, p0 = mBase & 1023;
    const int g64 = tx * 4 + wn;
    const int cls = g64 % 3, h = g64 / 3;

#pragma unroll
    for (int pass = 0; pass < 2; ++pass) {
        if (cls == 0) {
            // q: row-major (B,P,768)
#pragma unroll
            for (int mf = 0; mf < 4; ++mf)
#pragma unroll
                for (int nf = 0; nf < 4; ++nf)
#pragma unroll
                    for (int i = 0; i < 4; ++i)
                        slot[(mf * 16 + quad * 4 + i) * 72 + nf * 16 + m16] =
                            (bf16_t)acc[pass * 4 + mf][nf][i];
            asm volatile("s_waitcnt lgkmcnt(0)" ::: "memory");
            __builtin_amdgcn_sched_barrier(0);
#pragma unroll
            for (int j = 0; j < 8; ++j) {
                int r = j * 8 + (lane >> 3), cc = lane & 7;
                bf16x8 val = *(const bf16x8*)(slot + r * 72 + cc * 8);
                *(bf16x8*)(q + ((size_t)(b * 1024 + p0 + wm * 128 + pass * 64 + r)) * 768 +
                           h * 64 + cc * 8) = val;
            }
        } else {
            // k/v: transposed (B,H,64,P) via per-wave [c][72] transpose
            bf16_t* dst = (cls == 1) ? kt : vt;
            const size_t bh = (size_t)(b * 12 + h);
#pragma unroll
            for (int mf = 0; mf < 4; ++mf)
#pragma unroll
                for (int nf = 0; nf < 4; ++nf) {
                    int c = nf * 16 + m16;
                    union { bf16_t hh[4]; uint2 u; } pk;
#pragma unroll
                    for (int i = 0; i < 4; ++i)
                        pk.hh[i] = (bf16_t)acc[pass * 4 + mf][nf][i];
                    *(uint2*)(slot + c * 72 + mf * 16 + quad * 4) = pk.u;
                }
            asm volatile("s_waitcnt lgkmcnt(0)" ::: "memory");
            __builtin_amdgcn_sched_barrier(0);
#pragma unroll
            for (int j = 0; j < 8; ++j) {
                int c = (lane >> 3) + j * 8, r8 = (lane & 7) * 8;
                bf16x8 val = *(const bf16x8*)(slot + c * 72 + r8);
                *(bf16x8*)(dst + (bh * 64 + c) * 1024 + p0 + wm * 128 +
                           pass * 64 + r8) = val;
            }
        }
        if (pass == 0) {
            asm volatile("s_waitcnt lgkmcnt(0)" ::: "memory");
            __builtin_amdgcn_sched_barrier(0);
        }
    }
}

// ---------------------------------------------------------------------------
// kvu: fused T = K^T V (per head) then U = T @ lin_w slice, T never leaves
// the block. grid (192).
// ---------------------------------------------------------------------------
__global__ __launch_bounds__(256) void kvu_kernel(const bf16_t* __restrict__ kt,
                                                  const bf16_t* __restrict__ vt,
                                                  const bf16_t* __restrict__ lwT,
                                                  bf16_t* __restrict__ ut) {
    __shared__ float red[4 * 64 * 65];   // 66.6 KB
    const int bh = blockIdx.x;
    const int b = bh / NH, h = bh - b * NH;
    const bf16_t* Kb = kt + (size_t)bh * DH * PP;
    const bf16_t* Vb = vt + (size_t)bh * DH * PP;
    const int t = threadIdx.x;
    const int lane = t & 63, wave = t >> 6;
    const int m16 = lane & 15, quad = lane >> 4;
    const f32x4 z = {0.f, 0.f, 0.f, 0.f};

    // ---- phase A: T partials ----
    {
        f32x4 acc[4][4];
#pragma unroll
        for (int mm = 0; mm < 4; ++mm)
#pragma unroll
            for (int nn = 0; nn < 4; ++nn) acc[mm][nn] = z;
        for (int ks = 0; ks < 8; ++ks) {
            int kb = wave * 256 + ks * 32 + quad * 8;
            bf16x8 af[4], bfv[4];
#pragma unroll
            for (int mm = 0; mm < 4; ++mm)
                af[mm] = *(const bf16x8*)(Kb + (size_t)(mm * 16 + m16) * PP + kb);
#pragma unroll
            for (int nn = 0; nn < 4; ++nn)
                bfv[nn] = *(const bf16x8*)(Vb + (size_t)(nn * 16 + m16) * PP + kb);
#pragma unroll
            for (int mm = 0; mm < 4; ++mm)
#pragma unroll
                for (int nn = 0; nn < 4; ++nn)
                    acc[mm][nn] = __builtin_amdgcn_mfma_f32_16x16x32_bf16(
                        af[mm], bfv[nn], acc[mm][nn], 0, 0, 0);
        }
#pragma unroll
        for (int mm = 0; mm < 4; ++mm)
#pragma unroll
            for (int nn = 0; nn < 4; ++nn)
#pragma unroll
                for (int i = 0; i < 4; ++i)
                    red[wave * 4160 + (mm * 16 + quad * 4 + i) * 65 + nn * 16 + m16] =
                        acc[mm][nn][i];
    }
    __syncthreads();

    // ---- build T hi/lo frags (u-GEMM A operand layout) ----
    const int wm = wave >> 1, wn = wave & 1;
    bf16x8 ah[2][2], al[2][2];
#pragma unroll
    for (int mm = 0; mm < 2; ++mm)
#pragma unroll
        for (int ks = 0; ks < 2; ++ks) {
            int d1 = wm * 32 + mm * 16 + m16;
            int base = d1 * 65 + ks * 32 + quad * 8;
#pragma unroll
            for (int e = 0; e < 8; ++e) {
                float s = red[base + e] + red[4160 + base + e] +
                          red[8320 + base + e] + red[12480 + base + e];
                bf16_t hi = (bf16_t)s;
                ah[mm][ks][e] = hi;
                al[mm][ks][e] = (bf16_t)(s - (float)hi);
            }
        }

    // ---- phase B: U = T @ lwT-slice, 3 x 256-col chunks ----
#pragma unroll
    for (int ny = 0; ny < 3; ++ny) {
        const int nBase = ny * 256;
        f32x4 acc2[2][8];
#pragma unroll
        for (int mm = 0; mm < 2; ++mm)
#pragma unroll
            for (int nn = 0; nn < 8; ++nn) acc2[mm][nn] = z;
#pragma unroll
        for (int ks = 0; ks < 2; ++ks) {
            bf16x8 bfr[8];
#pragma unroll
            for (int nn = 0; nn < 8; ++nn)
                bfr[nn] = *(const bf16x8*)(
                    lwT + (size_t)(nBase + wn * 128 + nn * 16 + m16) * 768 +
                    h * 64 + ks * 32 + quad * 8);
#pragma unroll
            for (int mm = 0; mm < 2; ++mm)
#pragma unroll
                for (int nn = 0; nn < 8; ++nn) {
                    acc2[mm][nn] = __builtin_amdgcn_mfma_f32_16x16x32_bf16(
                        ah[mm][ks], bfr[nn], acc2[mm][nn], 0, 0, 0);
                    acc2[mm][nn] = __builtin_amdgcn_mfma_f32_16x16x32_bf16(
                        al[mm][ks], bfr[nn], acc2[mm][nn], 0, 0, 0);
                }
        }
#pragma unroll
        for (int mm = 0; mm < 2; ++mm)
#pragma unroll
            for (int nn = 0; nn < 8; ++nn) {
                int e  = nBase + wn * 128 + nn * 16 + m16;
                int d1 = wm * 32 + mm * 16 + quad * 4;
                union { bf16_t hh[4]; uint2 u; } pk;
#pragma unroll
                for (int i = 0; i < 4; ++i) pk.hh[i] = (bf16_t)acc2[mm][nn][i];
                *(uint2*)(ut + ((size_t)b * 768 + e) * 768 + h * 64 + d1) = pk.u;
            }
    }
}

// ---------------------------------------------------------------------------
// Final GEMM: out = relu(q @ U^b + lin_b) + x (fp32 out). 256x256 tile,
// grid (3,64) = 192 blocks, same phase-cadence core.
// ---------------------------------------------------------------------------
__global__ __launch_bounds__(512, 2) void gemm_out_kernel(const bf16_t* __restrict__ q,
                                                          const bf16_t* __restrict__ ut,
                                                          const float* __restrict__ linb,
                                                          const float* __restrict__ x,
                                                          float* __restrict__ out) {
    __shared__ bf16_t smem[49152];
    const int lb = blockIdx.y * 3 + blockIdx.x;
    const int id = (lb & 7) * 24 + (lb >> 3);   // 192 = 8*24, bijective
    const int tx = id % 3, ty = id / 3;
    const int mBase = ty * 256, nBase = tx * 256;
    const int b = mBase >> 10;

    f32x4 acc[8][4];
    core256_ph(q, ut + (size_t)b * 768 * 768, mBase, nBase, acc, smem);

    const int lane = threadIdx.x & 63, wave = threadIdx.x >> 6;
    const int wm = wave >> 2, wn = wave & 3;
    const int m16 = lane & 15, quad = lane >> 4;
#pragma unroll
    for (int mf = 0; mf < 8; ++mf) {
#pragma unroll
        for (int i = 0; i < 4; ++i) {
            size_t row = mBase + wm * 128 + mf * 16 + quad * 4 + i;
#pragma unroll
            for (int nf = 0; nf < 4; ++nf) {
                int col = nBase + wn * 64 + nf * 16 + m16;
                float v = acc[mf][nf][i] + linb[col];
                v = fmaxf(v, 0.f) + x[row * EE + col];
                out[row * EE + col] = v;
            }
        }
    }
}

// ---------------------------------------------------------------------------
// Launch
// ---------------------------------------------------------------------------
extern "C" void kernel_launch(void* const* d_in, const int* in_sizes, int n_in,
                              void* d_out, int out_size, void* d_ws, size_t ws_size,
                              hipStream_t stream) {
    const float* x    = (const float*)d_in[0];
    const float* lnw  = (const float*)d_in[1];
    const float* lnb  = (const float*)d_in[2];
    const float* qkvw = (const float*)d_in[3];
    const float* linw = (const float*)d_in[4];
    const float* linb = (const float*)d_in[5];
    float* out = (float*)d_out;
    char* ws = (char*)d_ws;

    // Workspace layout (bytes), total ~105.4 MB. Rotation:
    //   xn dead after gemm_qkv -> ut lives there (kvu reads kt/vt while
    //   writing ut, so ut must NOT alias kt/vt).
    float*  part  = (float*)(ws + 0);          //  8192 B
    float*  stats = (float*)(ws + 8192);       //   128 B
    bf16_t* xn    = (bf16_t*)(ws + 8448);      //  25165824 B
    bf16_t* qkvT  = (bf16_t*)(ws + 25174272);  //   3538944 B
    bf16_t* lwT   = (bf16_t*)(ws + 28713216);  //   1179648 B
    bf16_t* q     = (bf16_t*)(ws + 29892864);  //  25165824 B  (B,P,HID)
    bf16_t* kt    = (bf16_t*)(ws + 55058688);  //  25165824 B
    bf16_t* vt    = (bf16_t*)(ws + 80224512);  //  25165824 B -> end 105390336
    bf16_t* ut    = xn;                        //  18874368 B (xn dead after qkv)

    stats1_kernel<<<dim3(BB * 64), dim3(256), 0, stream>>>(x, part);
    prep_kernel<<<dim3(577), dim3(256), 0, stream>>>(qkvw, linw, part, qkvT, lwT, stats);
    ln_apply_kernel<<<dim3(6144), dim3(256), 0, stream>>>(x, lnw, lnb, stats, xn);
    gemm_qkv_kernel<<<dim3(9, 64), dim3(512), 0, stream>>>(xn, qkvT, q, kt, vt);
    kvu_kernel<<<dim3(192), dim3(256), 0, stream>>>(kt, vt, lwT, ut);
    gemm_out_kernel<<<dim3(3, 64), dim3(512), 0, stream>>>(q, ut, linb, x, out);
}

// Round 8
// 244.671 us; speedup vs baseline: 1.0533x; 1.0385x over previous
//
#include <hip/hip_runtime.h>
#include <hip/hip_bf16.h>
#include <cstdint>

// Problem constants
#define BB   16
#define PP   1024
#define EE   768
#define HID  768
#define NH   12
#define DH   64
#define NPB  (PP * EE)          // 786432 elements per batch
#define MROWS (BB * PP)         // 16384

typedef __bf16 bf16_t;
typedef __bf16 bf16x8 __attribute__((ext_vector_type(8)));
typedef float  f32x4  __attribute__((ext_vector_type(4)));

// Async global->LDS 16B DMA. LDS dest must be wave-uniform base + lane*16.
__device__ __forceinline__ void gld16(const void* g, void* l) {
    __builtin_amdgcn_global_load_lds(
        (const __attribute__((address_space(1))) void*)(uintptr_t)g,
        (__attribute__((address_space(3))) void*)(uint32_t)(uintptr_t)l,
        16, 0, 0);
}

// ---------------------------------------------------------------------------
// Stage 1: per-slice partial sums for batch-global LayerNorm stats
// ---------------------------------------------------------------------------
__global__ __launch_bounds__(256) void stats1_kernel(const float* __restrict__ x,
                                                     float* __restrict__ part) {
    int bid = blockIdx.x;
    int b = bid >> 6, s = bid & 63;
    const float4* xp = (const float4*)(x + (size_t)b * NPB + (size_t)s * 12288);
    float sum = 0.f, ss = 0.f;
#pragma unroll
    for (int i = 0; i < 12; ++i) {
        float4 v = xp[i * 256 + threadIdx.x];
        sum += v.x + v.y + v.z + v.w;
        ss  += v.x * v.x + v.y * v.y + v.z * v.z + v.w * v.w;
    }
#pragma unroll
    for (int off = 32; off > 0; off >>= 1) {
        sum += __shfl_down(sum, off, 64);
        ss  += __shfl_down(ss,  off, 64);
    }
    __shared__ float tmp[8];
    int wave = threadIdx.x >> 6, lane = threadIdx.x & 63;
    if (lane == 0) { tmp[wave * 2] = sum; tmp[wave * 2 + 1] = ss; }
    __syncthreads();
    if (threadIdx.x == 0) {
        part[bid * 2]     = tmp[0] + tmp[2] + tmp[4] + tmp[6];
        part[bid * 2 + 1] = tmp[1] + tmp[3] + tmp[5] + tmp[7];
    }
}

// ---------------------------------------------------------------------------
// prep: LDS-tiled weight transposes (coalesced both sides) + stats finalize.
// blocks [0,432): qkvT tiles ; [432,576): lwT tiles ; 576: stats2.
// ---------------------------------------------------------------------------
__global__ __launch_bounds__(256) void prep_kernel(const float* __restrict__ qkvw,
                                                   const float* __restrict__ linw,
                                                   const float* __restrict__ part,
                                                   bf16_t* __restrict__ qkvT,
                                                   bf16_t* __restrict__ lwT,
                                                   float* __restrict__ stats) {
    int bid = blockIdx.x;
    if (bid < 576) {
        __shared__ float lds[64][65];
        const float* src; bf16_t* dst; int r0, c0, W;
        if (bid < 432) {
            int tr = bid / 36, tc = bid - tr * 36;
            r0 = tr * 64; c0 = tc * 64; src = qkvw; W = 2304; dst = qkvT;
        } else {
            int bb = bid - 432;
            int tr = bb / 12, tc = bb - tr * 12;
            r0 = tr * 64; c0 = tc * 64; src = linw; W = 768; dst = lwT;
        }
        int t = threadIdx.x;
        int rr = t >> 4, cc4 = (t & 15) * 4;
#pragma unroll
        for (int j = 0; j < 4; ++j) {
            float4 v = *(const float4*)(src + (size_t)(r0 + rr + j * 16) * W + c0 + cc4);
            lds[rr + j * 16][cc4 + 0] = v.x;
            lds[rr + j * 16][cc4 + 1] = v.y;
            lds[rr + j * 16][cc4 + 2] = v.z;
            lds[rr + j * 16][cc4 + 3] = v.w;
        }
        __syncthreads();
        int cl = t >> 3, rgl = (t & 7) * 8;
#pragma unroll
        for (int jj = 0; jj < 2; ++jj) {
            int c = jj * 32 + cl;
            union { bf16_t h[8]; uint4 u; } o;
#pragma unroll
            for (int k = 0; k < 8; ++k) o.h[k] = (bf16_t)lds[rgl + k][c];
            *(uint4*)(dst + (size_t)(c0 + c) * 768 + r0 + rgl) = o.u;
        }
    } else {
        int wave = threadIdx.x >> 6, lane = threadIdx.x & 63;
#pragma unroll
        for (int j = 0; j < 4; ++j) {
            int b = wave * 4 + j;
            float sum = part[(b * 64 + lane) * 2];
            float ss  = part[(b * 64 + lane) * 2 + 1];
#pragma unroll
            for (int off = 32; off > 0; off >>= 1) {
                sum += __shfl_down(sum, off, 64);
                ss  += __shfl_down(ss,  off, 64);
            }
            if (lane == 0) {
                const float inv_n = 1.f / (float)NPB;
                float mean = sum * inv_n;
                float var  = ss * inv_n - mean * mean;
                stats[b * 2]     = mean;
                stats[b * 2 + 1] = rsqrtf(var + 1e-5f);
            }
        }
    }
}

__global__ __launch_bounds__(256) void ln_apply_kernel(const float* __restrict__ x,
                                                       const float* __restrict__ lnw,
                                                       const float* __restrict__ lnb,
                                                       const float* __restrict__ stats,
                                                       bf16_t* __restrict__ xn) {
    int i = (blockIdx.x * 256 + threadIdx.x) * 8;
    int b = i / NPB;
    int r = i - b * NPB;
    float mean = stats[b * 2], rstd = stats[b * 2 + 1];
    float4 x0 = *(const float4*)(x + i),     x1 = *(const float4*)(x + i + 4);
    float4 w0 = *(const float4*)(lnw + r),   w1 = *(const float4*)(lnw + r + 4);
    float4 c0 = *(const float4*)(lnb + r),   c1 = *(const float4*)(lnb + r + 4);
    union { bf16_t h[8]; uint4 u; } o;
    o.h[0] = (bf16_t)((x0.x - mean) * rstd * w0.x + c0.x);
    o.h[1] = (bf16_t)((x0.y - mean) * rstd * w0.y + c0.y);
    o.h[2] = (bf16_t)((x0.z - mean) * rstd * w0.z + c0.z);
    o.h[3] = (bf16_t)((x0.w - mean) * rstd * w0.w + c0.w);
    o.h[4] = (bf16_t)((x1.x - mean) * rstd * w1.x + c1.x);
    o.h[5] = (bf16_t)((x1.y - mean) * rstd * w1.y + c1.y);
    o.h[6] = (bf16_t)((x1.z - mean) * rstd * w1.z + c1.z);
    o.h[7] = (bf16_t)((x1.w - mean) * rstd * w1.w + c1.w);
    *(uint4*)(xn + i) = o.u;
}

// ---------------------------------------------------------------------------
// Shared core (gemm_out): 128x128 tile, BK=32, TRIPLE-buffered (48KB ->
// 3 blocks/CU), counted vmcnt(8), 4 waves (2Mx2N, wave tile 64x64).
// LDS lines 128B = paired rows (r | r+64), chunk slot rotated by line&7
// (2-way free); staging source pre-swizzled to match.
// ---------------------------------------------------------------------------
__device__ __forceinline__ void core128_bk32(const bf16_t* __restrict__ A,
                                             const bf16_t* __restrict__ Bt,
                                             int mBase, int nBase,
                                             f32x4 acc[4][4], bf16_t* smem) {
    const int t = threadIdx.x, lane = t & 63, wave = t >> 6;
    const int wm = wave >> 1, wn = wave & 1;
    const int m16 = lane & 15, quad = lane >> 4;

    const bf16_t* gsrc[4];
    int ldst[4];
#pragma unroll
    for (int j = 0; j < 2; ++j) {
        int c = t + 256 * j;
        int l = c >> 3, lg = ((c & 7) - (l & 7)) & 7;
        int row = l + (lg >> 2) * 64, kc = lg & 3;
        gsrc[j]     = A  + (size_t)(mBase + row) * 768 + kc * 8;
        ldst[j]     = c * 8;
        gsrc[2 + j] = Bt + (size_t)(nBase + row) * 768 + kc * 8;
        ldst[2 + j] = 4096 + c * 8;
    }

    int aOff[4], bOff[4];
#pragma unroll
    for (int f = 0; f < 4; ++f) {
        aOff[f] = (f * 16 + m16) * 64 + (((wm * 4 + quad) + (m16 & 7)) & 7) * 8;
        bOff[f] = 4096 + (f * 16 + m16) * 64 + (((wn * 4 + quad) + (m16 & 7)) & 7) * 8;
    }

    const f32x4 z = {0.f, 0.f, 0.f, 0.f};
#pragma unroll
    for (int mf = 0; mf < 4; ++mf)
#pragma unroll
        for (int nf = 0; nf < 4; ++nf) acc[mf][nf] = z;

    // prologue: stage steps 0,1 into bufs 0,1
#pragma unroll
    for (int j = 0; j < 4; ++j) gld16(gsrc[j], smem + ldst[j]);
#pragma unroll
    for (int j = 0; j < 4; ++j) gld16(gsrc[j] + 32, smem + 8192 + ldst[j]);

#pragma unroll
    for (int step = 0; step < 24; ++step) {
        const int cur = (step % 3) * 8192;
        asm volatile("s_waitcnt lgkmcnt(0)" ::: "memory");
        __builtin_amdgcn_sched_barrier(0);
        __builtin_amdgcn_s_barrier();
        if (step + 2 < 24) {
            const int nb = ((step + 2) % 3) * 8192;
            const int kq = (step + 2) * 32;
#pragma unroll
            for (int j = 0; j < 4; ++j)
                gld16(gsrc[j] + kq, smem + nb + ldst[j]);
        }
        if (step < 22)       asm volatile("s_waitcnt vmcnt(8)" ::: "memory");
        else if (step == 22) asm volatile("s_waitcnt vmcnt(4)" ::: "memory");
        else                 asm volatile("s_waitcnt vmcnt(0)" ::: "memory");
        __builtin_amdgcn_sched_barrier(0);
        __builtin_amdgcn_s_barrier();

        bf16x8 af[4], bfv[4];
#pragma unroll
        for (int f = 0; f < 4; ++f) {
            af[f]  = *(const bf16x8*)(smem + cur + aOff[f]);
            bfv[f] = *(const bf16x8*)(smem + cur + bOff[f]);
        }
        __builtin_amdgcn_s_setprio(1);
#pragma unroll
        for (int mf = 0; mf < 4; ++mf)
#pragma unroll
            for (int nf = 0; nf < 4; ++nf)
                acc[mf][nf] = __builtin_amdgcn_mfma_f32_16x16x32_bf16(
                    af[mf], bfv[nf], acc[mf][nf], 0, 0, 0);
        __builtin_amdgcn_s_setprio(0);
    }
}

// ---------------------------------------------------------------------------
// GEMM1 (R4-best restore): proj = xn @ qkv. Tile 128x256, 4 waves (2Mx2N),
// BK=32, TRIPLE-buffered (72KB, 2 blocks/CU), counted vmcnt(12).
// grid (9,128) = 1152 blocks, 256 thr.
// ---------------------------------------------------------------------------
__global__ __launch_bounds__(256, 2) void gemm_qkv_kernel(const bf16_t* __restrict__ xn,
                                                          const bf16_t* __restrict__ qkvT,
                                                          bf16_t* __restrict__ q,
                                                          bf16_t* __restrict__ kt,
                                                          bf16_t* __restrict__ vt) {
    __shared__ bf16_t smem[36864];   // 72KB: 3 x (A 8KB | B 16KB)
    const int t = threadIdx.x, lane = t & 63, wave = t >> 6;
    const int wm = wave >> 1, wn = wave & 1;
    const int m16 = lane & 15, quad = lane >> 4;

    // XCD swizzle: 1152 blocks = 8 * 144, bijective.
    const int lb = blockIdx.y * 9 + blockIdx.x;
    const int id = (lb & 7) * 144 + (lb >> 3);
    const int tx = id % 9, ty = id / 9;
    const int mBase = ty * 128, nBase = tx * 256;

    const bf16_t* gsrc[6];
    int ldst[6];
#pragma unroll
    for (int j = 0; j < 2; ++j) {
        int c = t + 256 * j;
        int l = c >> 3, lg = ((c & 7) - (l & 7)) & 7;
        gsrc[j] = xn + (size_t)(mBase + l + (lg >> 2) * 64) * 768 + (lg & 3) * 8;
        ldst[j] = c * 8;
    }
#pragma unroll
    for (int j = 0; j < 4; ++j) {
        int c = t + 256 * j;
        int l = c >> 3, lg = ((c & 7) - (l & 7)) & 7;
        gsrc[2 + j] = qkvT + (size_t)(nBase + l + (lg >> 2) * 128) * 768 + (lg & 3) * 8;
        ldst[2 + j] = 4096 + c * 8;
    }

    int aOff[4], bOff[8];
#pragma unroll
    for (int mf = 0; mf < 4; ++mf)
        aOff[mf] = (mf * 16 + m16) * 64 + (((wm * 4 + quad) + (m16 & 7)) & 7) * 8;
#pragma unroll
    for (int nf = 0; nf < 8; ++nf)
        bOff[nf] = 4096 + (nf * 16 + m16) * 64 + (((wn * 4 + quad) + (m16 & 7)) & 7) * 8;

    f32x4 acc[4][8];
    const f32x4 z = {0.f, 0.f, 0.f, 0.f};
#pragma unroll
    for (int mf = 0; mf < 4; ++mf)
#pragma unroll
        for (int nf = 0; nf < 8; ++nf) acc[mf][nf] = z;

    // prologue: stage steps 0 and 1 into bufs 0,1 (12 loads in flight)
#pragma unroll
    for (int j = 0; j < 6; ++j) gld16(gsrc[j], smem + ldst[j]);
#pragma unroll
    for (int j = 0; j < 6; ++j) gld16(gsrc[j] + 32, smem + 12288 + ldst[j]);

#pragma unroll
    for (int step = 0; step < 24; ++step) {
        const int cur = (step % 3) * 12288;
        asm volatile("s_waitcnt lgkmcnt(0)" ::: "memory");
        __builtin_amdgcn_sched_barrier(0);
        __builtin_amdgcn_s_barrier();
        if (step + 2 < 24) {
            const int nb = ((step + 2) % 3) * 12288;
            const int kq = (step + 2) * 32;
#pragma unroll
            for (int j = 0; j < 6; ++j)
                gld16(gsrc[j] + kq, smem + nb + ldst[j]);
        }
        if (step < 22)       asm volatile("s_waitcnt vmcnt(12)" ::: "memory");
        else if (step == 22) asm volatile("s_waitcnt vmcnt(6)"  ::: "memory");
        else                 asm volatile("s_waitcnt vmcnt(0)"  ::: "memory");
        __builtin_amdgcn_sched_barrier(0);
        __builtin_amdgcn_s_barrier();    // buf[step] globally ready

        bf16x8 af[4], bf0[4], bf1[4];
#pragma unroll
        for (int mf = 0; mf < 4; ++mf)
            af[mf] = *(const bf16x8*)(smem + cur + aOff[mf]);
#pragma unroll
        for (int nf = 0; nf < 4; ++nf)
            bf0[nf] = *(const bf16x8*)(smem + cur + bOff[nf]);
        __builtin_amdgcn_s_setprio(1);
#pragma unroll
        for (int mf = 0; mf < 4; ++mf)
#pragma unroll
            for (int nf = 0; nf < 4; ++nf)
                acc[mf][nf] = __builtin_amdgcn_mfma_f32_16x16x32_bf16(
                    af[mf], bf0[nf], acc[mf][nf], 0, 0, 0);
        __builtin_amdgcn_s_setprio(0);
        __builtin_amdgcn_s_barrier();    // mid-step phase barrier
#pragma unroll
        for (int nf = 0; nf < 4; ++nf)
            bf1[nf] = *(const bf16x8*)(smem + cur + bOff[4 + nf]);
        __builtin_amdgcn_s_setprio(1);
#pragma unroll
        for (int mf = 0; mf < 4; ++mf)
#pragma unroll
            for (int nf = 0; nf < 4; ++nf)
                acc[mf][4 + nf] = __builtin_amdgcn_mfma_f32_16x16x32_bf16(
                    af[mf], bf1[nf], acc[mf][4 + nf], 0, 0, 0);
        __builtin_amdgcn_s_setprio(0);
    }

    // ---- per-wave epilogue, private 9KB slot (64 x 72 el) ----
    asm volatile("s_waitcnt lgkmcnt(0)" ::: "memory");
    __builtin_amdgcn_sched_barrier(0);
    bf16_t* slot = smem + wave * 4608;
    const int b = mBase >> 10, p0 = mBase & 1023;

#pragma unroll
    for (int half = 0; half < 2; ++half) {
        const int g64 = tx * 4 + wn * 2 + half;
        const int cls = g64 % 3, h = g64 / 3;
        if (cls == 0) {
            // q: row-major (B,P,768)
#pragma unroll
            for (int mf = 0; mf < 4; ++mf)
#pragma unroll
                for (int nfl = 0; nfl < 4; ++nfl)
#pragma unroll
                    for (int i = 0; i < 4; ++i)
                        slot[(mf * 16 + quad * 4 + i) * 72 + nfl * 16 + m16] =
                            (bf16_t)acc[mf][half * 4 + nfl][i];
            asm volatile("s_waitcnt lgkmcnt(0)" ::: "memory");
            __builtin_amdgcn_sched_barrier(0);
#pragma unroll
            for (int j = 0; j < 8; ++j) {
                int r = j * 8 + (lane >> 3), cc = lane & 7;
                bf16x8 val = *(const bf16x8*)(slot + r * 72 + cc * 8);
                *(bf16x8*)(q + ((size_t)(b * 1024 + p0 + wm * 64 + r)) * 768 +
                           h * 64 + cc * 8) = val;
            }
        } else {
            // k/v: transposed (B,H,64,P) via per-wave [c][72] transpose
            bf16_t* dst = (cls == 1) ? kt : vt;
            const size_t bh = (size_t)(b * 12 + h);
#pragma unroll
            for (int mf = 0; mf < 4; ++mf)
#pragma unroll
                for (int nfl = 0; nfl < 4; ++nfl) {
                    int c = nfl * 16 + m16;
                    union { bf16_t hh[4]; uint2 u; } pk;
#pragma unroll
                    for (int i = 0; i < 4; ++i)
                        pk.hh[i] = (bf16_t)acc[mf][half * 4 + nfl][i];
                    *(uint2*)(slot + c * 72 + mf * 16 + quad * 4) = pk.u;
                }
            asm volatile("s_waitcnt lgkmcnt(0)" ::: "memory");
            __builtin_amdgcn_sched_barrier(0);
#pragma unroll
            for (int j = 0; j < 8; ++j) {
                int c = (lane >> 3) + j * 8, r8 = (lane & 7) * 8;
                bf16x8 val = *(const bf16x8*)(slot + c * 72 + r8);
                *(bf16x8*)(dst + (bh * 64 + c) * 1024 + p0 + wm * 64 + r8) = val;
            }
        }
        if (half == 0) {
            asm volatile("s_waitcnt lgkmcnt(0)" ::: "memory");
            __builtin_amdgcn_sched_barrier(0);
        }
    }
}

// ---------------------------------------------------------------------------
// kvu: fused T = K^T V (per head) then U = T @ lin_w slice, T never leaves
// the block. grid (192).
// ---------------------------------------------------------------------------
__global__ __launch_bounds__(256) void kvu_kernel(const bf16_t* __restrict__ kt,
                                                  const bf16_t* __restrict__ vt,
                                                  const bf16_t* __restrict__ lwT,
                                                  bf16_t* __restrict__ ut) {
    __shared__ float red[4 * 64 * 65];   // 66.6 KB
    const int bh = blockIdx.x;
    const int b = bh / NH, h = bh - b * NH;
    const bf16_t* Kb = kt + (size_t)bh * DH * PP;
    const bf16_t* Vb = vt + (size_t)bh * DH * PP;
    const int t = threadIdx.x;
    const int lane = t & 63, wave = t >> 6;
    const int m16 = lane & 15, quad = lane >> 4;
    const f32x4 z = {0.f, 0.f, 0.f, 0.f};

    // ---- phase A: T partials ----
    {
        f32x4 acc[4][4];
#pragma unroll
        for (int mm = 0; mm < 4; ++mm)
#pragma unroll
            for (int nn = 0; nn < 4; ++nn) acc[mm][nn] = z;
        for (int ks = 0; ks < 8; ++ks) {
            int kb = wave * 256 + ks * 32 + quad * 8;
            bf16x8 af[4], bfv[4];
#pragma unroll
            for (int mm = 0; mm < 4; ++mm)
                af[mm] = *(const bf16x8*)(Kb + (size_t)(mm * 16 + m16) * PP + kb);
#pragma unroll
            for (int nn = 0; nn < 4; ++nn)
                bfv[nn] = *(const bf16x8*)(Vb + (size_t)(nn * 16 + m16) * PP + kb);
#pragma unroll
            for (int mm = 0; mm < 4; ++mm)
#pragma unroll
                for (int nn = 0; nn < 4; ++nn)
                    acc[mm][nn] = __builtin_amdgcn_mfma_f32_16x16x32_bf16(
                        af[mm], bfv[nn], acc[mm][nn], 0, 0, 0);
        }
#pragma unroll
        for (int mm = 0; mm < 4; ++mm)
#pragma unroll
            for (int nn = 0; nn < 4; ++nn)
#pragma unroll
                for (int i = 0; i < 4; ++i)
                    red[wave * 4160 + (mm * 16 + quad * 4 + i) * 65 + nn * 16 + m16] =
                        acc[mm][nn][i];
    }
    __syncthreads();

    // ---- build T hi/lo frags (u-GEMM A operand layout) ----
    const int wm = wave >> 1, wn = wave & 1;
    bf16x8 ah[2][2], al[2][2];
#pragma unroll
    for (int mm = 0; mm < 2; ++mm)
#pragma unroll
        for (int ks = 0; ks < 2; ++ks) {
            int d1 = wm * 32 + mm * 16 + m16;
            int base = d1 * 65 + ks * 32 + quad * 8;
#pragma unroll
            for (int e = 0; e < 8; ++e) {
                float s = red[base + e] + red[4160 + base + e] +
                          red[8320 + base + e] + red[12480 + base + e];
                bf16_t hi = (bf16_t)s;
                ah[mm][ks][e] = hi;
                al[mm][ks][e] = (bf16_t)(s - (float)hi);
            }
        }

    // ---- phase B: U = T @ lwT-slice, 3 x 256-col chunks ----
#pragma unroll
    for (int ny = 0; ny < 3; ++ny) {
        const int nBase = ny * 256;
        f32x4 acc2[2][8];
#pragma unroll
        for (int mm = 0; mm < 2; ++mm)
#pragma unroll
            for (int nn = 0; nn < 8; ++nn) acc2[mm][nn] = z;
#pragma unroll
        for (int ks = 0; ks < 2; ++ks) {
            bf16x8 bfr[8];
#pragma unroll
            for (int nn = 0; nn < 8; ++nn)
                bfr[nn] = *(const bf16x8*)(
                    lwT + (size_t)(nBase + wn * 128 + nn * 16 + m16) * 768 +
                    h * 64 + ks * 32 + quad * 8);
#pragma unroll
            for (int mm = 0; mm < 2; ++mm)
#pragma unroll
                for (int nn = 0; nn < 8; ++nn) {
                    acc2[mm][nn] = __builtin_amdgcn_mfma_f32_16x16x32_bf16(
                        ah[mm][ks], bfr[nn], acc2[mm][nn], 0, 0, 0);
                    acc2[mm][nn] = __builtin_amdgcn_mfma_f32_16x16x32_bf16(
                        al[mm][ks], bfr[nn], acc2[mm][nn], 0, 0, 0);
                }
        }
#pragma unroll
        for (int mm = 0; mm < 2; ++mm)
#pragma unroll
            for (int nn = 0; nn < 8; ++nn) {
                int e  = nBase + wn * 128 + nn * 16 + m16;
                int d1 = wm * 32 + mm * 16 + quad * 4;
                union { bf16_t hh[4]; uint2 u; } pk;
#pragma unroll
                for (int i = 0; i < 4; ++i) pk.hh[i] = (bf16_t)acc2[mm][nn][i];
                *(uint2*)(ut + ((size_t)b * 768 + e) * 768 + h * 64 + d1) = pk.u;
            }
    }
}

// ---------------------------------------------------------------------------
// Final GEMM: out = relu(q @ U^b + lin_b) + x (fp32 out). grid (6,128) = 768
// blocks = 3 exact rounds at 3 blk/CU. Epilogue: acc -> fp32 LDS (stride 68,
// 2-way free) -> float4 read-back fused with bias/relu/x-add -> float4
// stores (256B-contiguous segments). x read as float4 likewise.
// ---------------------------------------------------------------------------
__global__ __launch_bounds__(256, 3) void gemm_out_kernel(const bf16_t* __restrict__ q,
                                                          const bf16_t* __restrict__ ut,
                                                          const float* __restrict__ linb,
                                                          const float* __restrict__ x,
                                                          float* __restrict__ out) {
    __shared__ bf16_t smem[24576];   // 48KB K-loop; epilogue reuse as fp32
    const int lb  = blockIdx.y * 6 + blockIdx.x;
    const int swz = (lb & 7) * 96 + (lb >> 3);      // 768/8 = 96 per XCD
    const int tx  = swz % 6, ty = swz / 6;
    const int mBase = ty * 128, nBase = tx * 128;
    const int b = mBase >> 10;

    f32x4 acc[4][4];
    core128_bk32(q, ut + (size_t)b * 768 * 768, mBase, nBase, acc, smem);

    const int lane = threadIdx.x & 63, wave = threadIdx.x >> 6;
    const int wm = wave >> 1, wn = wave & 1;
    const int m16 = lane & 15, quad = lane >> 4;

    asm volatile("s_waitcnt lgkmcnt(0)" ::: "memory");
    __builtin_amdgcn_sched_barrier(0);
    __syncthreads();   // all waves done with K-loop LDS before fp32 reuse

    float* fslot = (float*)smem + wave * 2176;   // 32 x 68 fp32 per wave
    const int cl = lane & 15, rq = lane >> 4;
    const int colBase = nBase + wn * 64;
    const float4 lb4 = *(const float4*)(linb + colBase + cl * 4);

#pragma unroll
    for (int p = 0; p < 2; ++p) {
        // rows p*32 .. p*32+31 of the wave's 64x64 tile
#pragma unroll
        for (int mm = 0; mm < 2; ++mm)
#pragma unroll
            for (int nn = 0; nn < 4; ++nn)
#pragma unroll
                for (int i = 0; i < 4; ++i)
                    fslot[(mm * 16 + quad * 4 + i) * 68 + nn * 16 + m16] =
                        acc[p * 2 + mm][nn][i];
        asm volatile("s_waitcnt lgkmcnt(0)" ::: "memory");
        __builtin_amdgcn_sched_barrier(0);
#pragma unroll
        for (int j = 0; j < 8; ++j) {
            int lr = j * 4 + rq;
            size_t row = (size_t)(mBase + wm * 64 + p * 32 + lr);
            float4 v4 = *(const float4*)(fslot + lr * 68 + cl * 4);
            float4 x4 = *(const float4*)(x + row * EE + colBase + cl * 4);
            float4 o4;
            o4.x = fmaxf(v4.x + lb4.x, 0.f) + x4.x;
            o4.y = fmaxf(v4.y + lb4.y, 0.f) + x4.y;
            o4.z = fmaxf(v4.z + lb4.z, 0.f) + x4.z;
            o4.w = fmaxf(v4.w + lb4.w, 0.f) + x4.w;
            *(float4*)(out + row * EE + colBase + cl * 4) = o4;
        }
        if (p == 0) {
            asm volatile("s_waitcnt lgkmcnt(0)" ::: "memory");
            __builtin_amdgcn_sched_barrier(0);
        }
    }
}

// ---------------------------------------------------------------------------
// Launch
// ---------------------------------------------------------------------------
extern "C" void kernel_launch(void* const* d_in, const int* in_sizes, int n_in,
                              void* d_out, int out_size, void* d_ws, size_t ws_size,
                              hipStream_t stream) {
    const float* x    = (const float*)d_in[0];
    const float* lnw  = (const float*)d_in[1];
    const float* lnb  = (const float*)d_in[2];
    const float* qkvw = (const float*)d_in[3];
    const float* linw = (const float*)d_in[4];
    const float* linb = (const float*)d_in[5];
    float* out = (float*)d_out;
    char* ws = (char*)d_ws;

    // Workspace layout (bytes), total ~105.4 MB. Rotation:
    //   xn dead after gemm_qkv -> ut lives there (kvu reads kt/vt while
    //   writing ut, so ut must NOT alias kt/vt).
    float*  part  = (float*)(ws + 0);          //  8192 B
    float*  stats = (float*)(ws + 8192);       //   128 B
    bf16_t* xn    = (bf16_t*)(ws + 8448);      //  25165824 B
    bf16_t* qkvT  = (bf16_t*)(ws + 25174272);  //   3538944 B
    bf16_t* lwT   = (bf16_t*)(ws + 28713216);  //   1179648 B
    bf16_t* q     = (bf16_t*)(ws + 29892864);  //  25165824 B  (B,P,HID)
    bf16_t* kt    = (bf16_t*)(ws + 55058688);  //  25165824 B
    bf16_t* vt    = (bf16_t*)(ws + 80224512);  //  25165824 B -> end 105390336
    bf16_t* ut    = xn;                        //  18874368 B (xn dead after qkv)

    stats1_kernel<<<dim3(BB * 64), dim3(256), 0, stream>>>(x, part);
    prep_kernel<<<dim3(577), dim3(256), 0, stream>>>(qkvw, linw, part, qkvT, lwT, stats);
    ln_apply_kernel<<<dim3(6144), dim3(256), 0, stream>>>(x, lnw, lnb, stats, xn);
    gemm_qkv_kernel<<<dim3(9, 128), dim3(256), 0, stream>>>(xn, qkvT, q, kt, vt);
    kvu_kernel<<<dim3(192), dim3(256), 0, stream>>>(kt, vt, lwT, ut);
    gemm_out_kernel<<<dim3(6, 128), dim3(256), 0, stream>>>(q, ut, linb, x, out);
}